// Round 13
// baseline (93.314 us; speedup 1.0000x reference)
//
#include <hip/hip_runtime.h>

// B=2,G=1024,S=64,L=16,F=8 -> LF=128, ATT=128, RANK=32, HC=32, NH=4. NWIN=2048.
#define NWIN 2048

// ws layout (BYTE offsets). Total 86528 B (under proven 123392 budget).
#define QKVT8_OFF 0      // uchar [160][128]: rows 0-127 QT_tab^T x256 (fused Wq_u*M, incl 1/sqrt32)
                         //                   rows 128-159 Wkv_u^T x16
#define OT8_OFF  20480   // uchar [128][128]  O^T x128
#define W1T_OFF  36864   // short [128][128]  W1^T bf16 (x1)
#define W2T8_OFF 69632   // uchar [128][128]  W2^T x16
#define CVEC_OFF 86016   // float [128]

typedef __attribute__((ext_vector_type(8))) __bf16 bf16x8;
typedef __attribute__((ext_vector_type(8))) short s16x8;
typedef __attribute__((ext_vector_type(4))) short s16x4;
typedef __attribute__((ext_vector_type(4))) float f32x4;

static __device__ inline short f2bf(float f) {
    __bf16 b = (__bf16)f;
    return __builtin_bit_cast(short, b);
}
static __device__ inline float bf2f(short h) {
    unsigned u = ((unsigned)(unsigned short)h) << 16;
    return __builtin_bit_cast(float, u);
}
static __device__ inline bf16x8 ldbf8(const short* p) {
    return __builtin_bit_cast(bf16x8, *(const s16x8*)p);
}
static __device__ inline unsigned char f2fp8(float v) {
    return (unsigned char)__builtin_amdgcn_cvt_pk_fp8_f32(v, v, 0u, false);
}
static __device__ inline long ld8(const void* p) {
    return *(const long*)p;
}

// ---------------- precompute: fp8 tables (scales exact powers of 2) ----------------
__global__ __launch_bounds__(256) void fam_pre(
    const float* __restrict__ Wq_u, const float* __restrict__ Wq_v,
    const float* __restrict__ Wkv_u, const float* __restrict__ Wkv_v,
    const float* __restrict__ kv_b, const float* __restrict__ Wo_u,
    const float* __restrict__ Wo_v, const float* __restrict__ W1,
    const float* __restrict__ W2, unsigned char* __restrict__ ws8)
{
    const int b = blockIdx.x, tid = threadIdx.x;
    float* cvec = (float*)(ws8 + CVEC_OFF);
    if (b < 16) {
        __shared__ float Wv[4096];   // Wkv_v v-part [r][c]
        __shared__ float Wu[4096];   // Wo_u [att][u]
        __shared__ float N[4096];    // N[h][u][r]
        for (int i = tid; i < 4096; i += 256) {
            int r = i >> 7, c = i & 127;
            Wv[i] = Wkv_v[r*256 + 128 + c];
            Wu[i] = Wo_u[i];
        }
        __syncthreads();
        for (int i = tid; i < 4096; i += 256) {
            int h = i >> 10, u = (i >> 5) & 31, r = i & 31;
            float acc = 0.f;
            for (int c = 0; c < 32; ++c) acc += Wv[r*128 + h*32 + c] * Wu[(h*32 + c)*32 + u];
            N[i] = acc;
        }
        __syncthreads();
        for (int i = tid; i < 1024; i += 256) {
            int jj = i >> 7, hr = i & 127;
            int j = b*8 + jj, h = hr >> 5, r = hr & 31;
            float acc = 0.f;
            for (int u = 0; u < 32; ++u) acc += N[h*1024 + u*32 + r] * Wo_v[u*128 + j];
            ws8[OT8_OFF + j*128 + hr] = f2fp8(acc * 128.f);
        }
    } else if (b < 32) {
        short* w1t = (short*)(ws8 + W1T_OFF);
        int i0 = (b - 16) * 8;
        for (int t = tid; t < 1024; t += 256) {
            int ii = t >> 7, k = t & 127, i = i0 + ii;
            w1t[i*128 + k] = f2bf(W1[k*128 + i]);
        }
    } else if (b < 48) {
        int j0 = (b - 32) * 8;
        for (int t = tid; t < 1024; t += 256) {
            int jj = t >> 7, k = t & 127, j = j0 + jj;
            ws8[W2T8_OFF + j*128 + k] = f2fp8(W2[k*128 + j] * 16.f);
        }
    } else {
        // QKVT slices: sl = 0..7; each builds M redundantly, writes 16 QT rows + 4 KV rows
        const int sl = b - 48;
        __shared__ float Msh[4096];   // M[h][u][r] (incl 1/sqrt32)
        __shared__ float ov[32];
        const float sc = 0.17677669529663687f;  // 1/sqrt(32)
        for (int i = tid; i < 4096; i += 256) {
            int h = i >> 10, u = (i >> 5) & 31, r = i & 31;
            float acc = 0.f;
            for (int c = 0; c < 32; ++c)
                acc += Wq_v[u*128 + h*32 + c] * Wkv_v[r*256 + h*32 + c];
            Msh[i] = acc * sc;
        }
        __syncthreads();
        // QT_tab rows c (= output col): tab[c][k] = sum_u Wq_u[k][u]*M[h(c)][u][r(c)], x256
        for (int i = tid; i < 2048; i += 256) {
            int c = sl*16 + (i >> 7), k = i & 127;
            int h = c >> 5, r = c & 31;
            float acc = 0.f;
            for (int u = 0; u < 32; ++u) acc += Wq_u[k*32 + u] * Msh[h*1024 + u*32 + r];
            ws8[QKVT8_OFF + c*128 + k] = f2fp8(acc * 256.f);
        }
        // KV rows (x16)
        for (int i = tid; i < 512; i += 256) {
            int u = sl*4 + (i >> 7), k = i & 127;
            ws8[QKVT8_OFF + (128 + u)*128 + k] = f2fp8(Wkv_u[k*32 + u] * 16.f);
        }
        if (sl == 0) {
            if (tid < 32) {
                float a = 0.f;
                for (int att = 0; att < 128; ++att) a += kv_b[128 + att] * Wo_u[att*32 + tid];
                ov[tid] = a;
            }
            __syncthreads();
            if (tid < 128) {
                float a = 0.f;
                for (int u = 0; u < 32; ++u) a += ov[u] * Wo_v[u*128 + tid];
                cvec[tid] = a;
            }
        }
    }
}

// ---------------- main fused kernel: 1 block = 1 window, 4 waves ----------------
// R12 (proven) + fused QT projection: P3's qt GEMM folded into P2 via QT_tab.
// LDS 32000 B -> 5 blocks/CU. Scale ledger: h x1 | QTtab x256 | qt8 x64 |
// KVtab x16 | kv/v x4 | score acc x256 | P x64 | pu x8 | O x128 | t1 x8 | W2 x16.
#define SRA 136   // RA8/XB byte/short stride
#define SHQ 40    // KV8 byte stride
#define SHB 72    // HB8/KVT8 byte stride

#define SM_RA8   0        //  8704  h -> pu -> t1 (fp8 [64][SRA])
#define SM_KV8   8704     //  2560  hu_kv x4 fp8 [64][SHQ] (A of scores)
#define SM_KVT8  11264    //  2304  hu_kv^T x4 fp8 [32][SHB] (B of PV)
#define SM_HB8   13568    // 18432  per head [64][SHB]: qt8 then P8; later XB bf16 [64][136]
#define SM_TOTAL 32000

__global__ __launch_bounds__(256, 5) void fam_main(
    const float* __restrict__ x, const unsigned char* __restrict__ ws8,
    const float* __restrict__ gamma, const float* __restrict__ b1,
    const float* __restrict__ b2, const float* __restrict__ gmlp_p,
    float* __restrict__ out)
{
    __shared__ __align__(16) unsigned char SM[SM_TOTAL];
    unsigned char* RA8  = SM + SM_RA8;
    unsigned char* KV8  = SM + SM_KV8;
    unsigned char* KVT8 = SM + SM_KVT8;

    const float* cvec = (const float*)(ws8 + CVEC_OFF);
    const int tid = threadIdx.x;
    const int l   = tid & 63;
    const int wv  = tid >> 6;
    const int l15 = l & 15;
    const int lg  = l >> 4;
    const size_t base = (size_t)blockIdx.x * 8192;
    const float* __restrict__ xw   = x + base;
    float* __restrict__       outw = out + base;
    const int n0 = wv * 32;

    // ---- P1: LN1 -> h (fp8 x1) in RA8 ----
    {
        int s = tid >> 2, c = tid & 3;
        float4 xr1[8];
        float sum = 0.f, sq = 0.f;
        #pragma unroll
        for (int j = 0; j < 8; ++j) {
            xr1[j] = *(const float4*)&xw[s*128 + c*32 + j*4];
            sum += xr1[j].x + xr1[j].y + xr1[j].z + xr1[j].w;
            sq  += xr1[j].x*xr1[j].x + xr1[j].y*xr1[j].y + xr1[j].z*xr1[j].z + xr1[j].w*xr1[j].w;
        }
        sum += __shfl_xor(sum, 1); sq += __shfl_xor(sq, 1);
        sum += __shfl_xor(sum, 2); sq += __shfl_xor(sq, 2);
        float mean = sum * (1.f/128.f);
        float var  = sq * (1.f/128.f) - mean*mean;
        float rinv = rsqrtf(var + 1e-5f);
        #pragma unroll
        for (int j = 0; j < 8; ++j) {
            unsigned w = 0;
            w = __builtin_amdgcn_cvt_pk_fp8_f32((xr1[j].x - mean)*rinv, (xr1[j].y - mean)*rinv, w, false);
            w = __builtin_amdgcn_cvt_pk_fp8_f32((xr1[j].z - mean)*rinv, (xr1[j].w - mean)*rinv, w, true);
            *(unsigned*)&RA8[s*SRA + c*32 + j*4] = w;
        }
    }
    __syncthreads();   // B1

    // ---- P2 (fused): [QT(128) | KV(32)] = h @ QKVT8 ----
    // wave wv: strips wv (qt head wv>>1), wv+4 (qt head 2+(wv>>1)), and 6+wv (kv, wv>=2)
    {
        long bA[4], bB[4], bC[4];
        #pragma unroll
        for (int kb = 0; kb < 4; ++kb) {
            bA[kb] = ld8(ws8 + QKVT8_OFF + (wv*16 + l15)*128 + kb*32 + lg*8);
            bB[kb] = ld8(ws8 + QKVT8_OFF + ((wv + 4)*16 + l15)*128 + kb*32 + lg*8);
        }
        if (wv >= 2) {
            #pragma unroll
            for (int kb = 0; kb < 4; ++kb)
                bC[kb] = ld8(ws8 + QKVT8_OFF + ((6 + wv)*16 + l15)*128 + kb*32 + lg*8);
        }
        unsigned char* HBA = SM + SM_HB8 + (wv >> 1)*4608;        // head wv>>1
        unsigned char* HBB = SM + SM_HB8 + (2 + (wv >> 1))*4608;  // head 2+(wv>>1)
        const int rr = (wv & 1)*16 + l15;                          // col within head
        #pragma unroll
        for (int m = 0; m < 4; ++m) {
            long a[4];
            #pragma unroll
            for (int kb = 0; kb < 4; ++kb)
                a[kb] = ld8(RA8 + (m*16 + l15)*SRA + kb*32 + lg*8);
            f32x4 accA = {0.f,0.f,0.f,0.f}, accB = {0.f,0.f,0.f,0.f};
            #pragma unroll
            for (int kb = 0; kb < 4; ++kb) {
                accA = __builtin_amdgcn_mfma_f32_16x16x32_fp8_fp8(a[kb], bA[kb], accA, 0, 0, 0);
                accB = __builtin_amdgcn_mfma_f32_16x16x32_fp8_fp8(a[kb], bB[kb], accB, 0, 0, 0);
            }
            #pragma unroll
            for (int j = 0; j < 4; ++j) {
                int row = (m*16 + lg*4 + j)*SHB;
                HBA[row + rr] = f2fp8(accA[j] * 0.25f);   // qt8 = qt x64
                HBB[row + rr] = f2fp8(accB[j] * 0.25f);
            }
            if (wv >= 2) {
                f32x4 accC = {0.f,0.f,0.f,0.f};
                #pragma unroll
                for (int kb = 0; kb < 4; ++kb)
                    accC = __builtin_amdgcn_mfma_f32_16x16x32_fp8_fp8(a[kb], bC[kb], accC, 0, 0, 0);
                int u = (wv - 2)*16 + l15;
                #pragma unroll
                for (int j = 0; j < 4; ++j)
                    KV8[(m*16 + lg*4 + j)*SHQ + u] = f2fp8(accC[j] * 0.25f);   // kv x4
                unsigned w = 0;
                w = __builtin_amdgcn_cvt_pk_fp8_f32(accC[0]*0.25f, accC[1]*0.25f, w, false);
                w = __builtin_amdgcn_cvt_pk_fp8_f32(accC[2]*0.25f, accC[3]*0.25f, w, true);
                *(unsigned*)&KVT8[u*SHB + m*16 + lg*4] = w;                    // v x4
            }
        }
    }
    __syncthreads();   // B2: qt8 (all heads), kv, v complete

    // ---- P4/P5: per-head attention (h = wv); qt8 already in HB8h ----
    {
        const int h = wv;
        unsigned char* HB8h = SM + SM_HB8 + h*4608;
        // scores: S^T[t][s] (swapped operands), acc = score x256
        long av[4], bq[4];
        #pragma unroll
        for (int m = 0; m < 4; ++m) av[m] = ld8(KV8 + (m*16 + l15)*SHQ + lg*8);
        #pragma unroll
        for (int n = 0; n < 4; ++n) bq[n] = ld8(HB8h + (n*16 + l15)*SHB + lg*8);
        f32x4 cc[4][4];
        #pragma unroll
        for (int m = 0; m < 4; ++m)
            #pragma unroll
            for (int n = 0; n < 4; ++n) {
                f32x4 z = {0.f, 0.f, 0.f, 0.f};
                cc[m][n] = __builtin_amdgcn_mfma_f32_16x16x32_fp8_fp8(av[m], bq[n], z, 0, 0, 0);
            }
        // softmax over t (no max-reduce; scores tiny), P8 = P x64 (overwrites qt8 after reads)
        #pragma unroll
        for (int n = 0; n < 4; ++n) {
            float e[4][4];
            float sm = 0.f;
            #pragma unroll
            for (int m = 0; m < 4; ++m)
                #pragma unroll
                for (int j = 0; j < 4; ++j) {
                    e[m][j] = __expf(fminf(cc[m][n][j] * 0.00390625f, 30.f));
                    sm += e[m][j];
                }
            sm += __shfl_xor(sm, 16);
            sm += __shfl_xor(sm, 32);
            float rs64 = __builtin_amdgcn_rcpf(sm) * 64.f;
            int srow = (n*16 + l15) * SHB;
            #pragma unroll
            for (int m = 0; m < 4; ++m) {
                unsigned w = 0;
                w = __builtin_amdgcn_cvt_pk_fp8_f32(e[m][0]*rs64, e[m][1]*rs64, w, false);
                w = __builtin_amdgcn_cvt_pk_fp8_f32(e[m][2]*rs64, e[m][3]*rs64, w, true);
                *(unsigned*)&HB8h[srow + m*16 + lg*4] = w;
            }
        }
        // PV: pu = P @ V, acc = pu x256 -> pu8 = pu x8 into RA8
        long a8[4][2], b8[2][2];
        #pragma unroll
        for (int m = 0; m < 4; ++m)
            #pragma unroll
            for (int kb = 0; kb < 2; ++kb)
                a8[m][kb] = ld8(HB8h + (m*16 + l15)*SHB + kb*32 + lg*8);
        #pragma unroll
        for (int nn = 0; nn < 2; ++nn)
            #pragma unroll
            for (int kb = 0; kb < 2; ++kb)
                b8[nn][kb] = ld8(KVT8 + (nn*16 + l15)*SHB + kb*32 + lg*8);
        #pragma unroll
        for (int m = 0; m < 4; ++m)
            #pragma unroll
            for (int nn = 0; nn < 2; ++nn) {
                f32x4 acc = {0.f,0.f,0.f,0.f};
                acc = __builtin_amdgcn_mfma_f32_16x16x32_fp8_fp8(a8[m][0], b8[nn][0], acc, 0, 0, 0);
                acc = __builtin_amdgcn_mfma_f32_16x16x32_fp8_fp8(a8[m][1], b8[nn][1], acc, 0, 0, 0);
                #pragma unroll
                for (int j = 0; j < 4; ++j)
                    RA8[(m*16 + lg*4 + j)*SRA + h*32 + nn*16 + l15] = f2fp8(acc[j] * 0.03125f);
            }
    }
    __syncthreads();   // B3: pu8 in RA8 complete; HB8 dead -> XB

    float x1v[4][2][4];
    short* XB = (short*)(SM + SM_HB8);   // x1/h2 bf16 [64][136]

    // ---- P6: upd = pu8 @ O8 (acc = upd x1024); x1 = x + gm*(acc/1024 + cv) ----
    {
        float xr[4][2][4];
        #pragma unroll
        for (int m = 0; m < 4; ++m)
            #pragma unroll
            for (int nn = 0; nn < 2; ++nn)
                #pragma unroll
                for (int j = 0; j < 4; ++j)
                    xr[m][nn][j] = xw[(m*16 + lg*4 + j)*128 + n0 + nn*16 + l15];
        long bo[2][4];
        float cv[2], gm[2];
        #pragma unroll
        for (int nn = 0; nn < 2; ++nn) {
            int col = n0 + nn*16 + l15;
            #pragma unroll
            for (int kb = 0; kb < 4; ++kb)
                bo[nn][kb] = ld8(ws8 + OT8_OFF + col*128 + kb*32 + lg*8);
            cv[nn] = cvec[col];
            gm[nn] = gamma[col];
        }
        f32x4 acc[4][2];
        #pragma unroll
        for (int m = 0; m < 4; ++m)
            #pragma unroll
            for (int nn = 0; nn < 2; ++nn) acc[m][nn] = (f32x4){0.f,0.f,0.f,0.f};
        #pragma unroll
        for (int m = 0; m < 4; ++m) {
            long a[4];
            #pragma unroll
            for (int kb = 0; kb < 4; ++kb)
                a[kb] = ld8(RA8 + (m*16 + l15)*SRA + kb*32 + lg*8);
            #pragma unroll
            for (int kb = 0; kb < 4; ++kb)
                #pragma unroll
                for (int nn = 0; nn < 2; ++nn)
                    acc[m][nn] = __builtin_amdgcn_mfma_f32_16x16x32_fp8_fp8(a[kb], bo[nn][kb], acc[m][nn], 0, 0, 0);
        }
        // XB does not alias RA8: no interior barrier needed
        #pragma unroll
        for (int m = 0; m < 4; ++m)
            #pragma unroll
            for (int nn = 0; nn < 2; ++nn)
                #pragma unroll
                for (int j = 0; j < 4; ++j) {
                    int row = m*16 + lg*4 + j;
                    float v = xr[m][nn][j] + gm[nn] * (acc[m][nn][j] * 9.765625e-4f + cv[nn]);
                    x1v[m][nn][j] = v;
                    XB[row*SRA + n0 + nn*16 + l15] = f2bf(v);
                }
    }
    __syncthreads();   // B4: x1 bf16 in XB complete

    // ---- P7: LN2 on XB in place (bf16, proven) ----
    {
        int s = tid >> 2, c = tid & 3;
        float sum = 0.f, sq = 0.f;
        #pragma unroll
        for (int jj = 0; jj < 8; ++jj) {
            s16x4 hv = *(const s16x4*)&XB[s*SRA + c*32 + jj*4];
            #pragma unroll
            for (int e = 0; e < 4; ++e) {
                float f = bf2f(hv[e]);
                sum += f; sq += f*f;
            }
        }
        sum += __shfl_xor(sum, 1); sq += __shfl_xor(sq, 1);
        sum += __shfl_xor(sum, 2); sq += __shfl_xor(sq, 2);
        float mean = sum * (1.f/128.f);
        float var  = sq * (1.f/128.f) - mean*mean;
        float rinv = rsqrtf(var + 1e-5f);
        #pragma unroll
        for (int jj = 0; jj < 8; ++jj) {
            s16x4 hv = *(const s16x4*)&XB[s*SRA + c*32 + jj*4];
            s16x4 ov;
            #pragma unroll
            for (int e = 0; e < 4; ++e) ov[e] = f2bf((bf2f(hv[e]) - mean) * rinv);
            *(s16x4*)&XB[s*SRA + c*32 + jj*4] = ov;
        }
    }
    __syncthreads();   // B5: h2 in XB

    // ---- P8: t1 = gelu(h2 @ W1 + b1) (bf16 MFMA) -> t1 x8 fp8 into RA8 ----
    {
        const short* W1t = (const short*)(ws8 + W1T_OFF);
        bf16x8 bw1[2][4];
        float bb1[2];
        #pragma unroll
        for (int nn = 0; nn < 2; ++nn) {
            #pragma unroll
            for (int k = 0; k < 4; ++k)
                bw1[nn][k] = ldbf8(&W1t[(n0 + nn*16 + l15)*128 + k*32 + lg*8]);
            bb1[nn] = b1[n0 + nn*16 + l15];
        }
        #pragma unroll
        for (int m = 0; m < 4; ++m) {
            bf16x8 a[4];
            #pragma unroll
            for (int k = 0; k < 4; ++k)
                a[k] = ldbf8(&XB[(m*16 + l15)*SRA + k*32 + lg*8]);
            #pragma unroll
            for (int nn = 0; nn < 2; ++nn) {
                f32x4 acc = {0.f,0.f,0.f,0.f};
                #pragma unroll
                for (int k = 0; k < 4; ++k)
                    acc = __builtin_amdgcn_mfma_f32_16x16x32_bf16(a[k], bw1[nn][k], acc, 0, 0, 0);
                #pragma unroll
                for (int j = 0; j < 4; ++j) {
                    float t = acc[j] + bb1[nn];
                    float w = -1.5957691216057308f * (t + 0.044715f*t*t*t);
                    float g = t * __builtin_amdgcn_rcpf(1.f + __expf(w));
                    RA8[(m*16 + lg*4 + j)*SRA + n0 + nn*16 + l15] = f2fp8(g * 8.f);
                }
            }
        }
    }
    __syncthreads();   // B6: t1 x8 in RA8

    // ---- P9: m = t1 @ W2 (acc = m x128); out = x1(reg) + gmlp*(acc/128 + b2) ----
    {
        const float gmv = gmlp_p[0];
        long bw[2][4];
        float bb[2];
        #pragma unroll
        for (int nn = 0; nn < 2; ++nn) {
            int col = n0 + nn*16 + l15;
            #pragma unroll
            for (int kb = 0; kb < 4; ++kb)
                bw[nn][kb] = ld8(ws8 + W2T8_OFF + col*128 + kb*32 + lg*8);
            bb[nn] = b2[col];
        }
        #pragma unroll
        for (int m = 0; m < 4; ++m) {
            long a[4];
            #pragma unroll
            for (int kb = 0; kb < 4; ++kb)
                a[kb] = ld8(RA8 + (m*16 + l15)*SRA + kb*32 + lg*8);
            #pragma unroll
            for (int nn = 0; nn < 2; ++nn) {
                f32x4 acc = {0.f,0.f,0.f,0.f};
                #pragma unroll
                for (int kb = 0; kb < 4; ++kb)
                    acc = __builtin_amdgcn_mfma_f32_16x16x32_fp8_fp8(a[kb], bw[nn][kb], acc, 0, 0, 0);
                #pragma unroll
                for (int j = 0; j < 4; ++j)
                    outw[(m*16 + lg*4 + j)*128 + n0 + nn*16 + l15] =
                        x1v[m][nn][j] + gmv * (acc[j] * 0.0078125f + bb[nn]);
            }
        }
    }
}

extern "C" void kernel_launch(void* const* d_in, const int* in_sizes, int n_in,
                              void* d_out, int out_size, void* d_ws, size_t ws_size,
                              hipStream_t stream) {
    const float* x     = (const float*)d_in[0];
    const float* Wq_u  = (const float*)d_in[1];
    const float* Wq_v  = (const float*)d_in[2];
    const float* Wkv_u = (const float*)d_in[3];
    const float* Wkv_v = (const float*)d_in[4];
    const float* kv_b  = (const float*)d_in[5];
    const float* Wo_u  = (const float*)d_in[6];
    const float* Wo_v  = (const float*)d_in[7];
    const float* gamma = (const float*)d_in[8];
    const float* W1    = (const float*)d_in[9];
    const float* b1    = (const float*)d_in[10];
    const float* W2    = (const float*)d_in[11];
    const float* b2    = (const float*)d_in[12];
    const float* gmlp  = (const float*)d_in[13];
    unsigned char* ws8 = (unsigned char*)d_ws;
    float* out = (float*)d_out;

    fam_pre<<<56, 256, 0, stream>>>(Wq_u, Wq_v, Wkv_u, Wkv_v, kv_b, Wo_u, Wo_v, W1, W2, ws8);
    fam_main<<<NWIN, 256, 0, stream>>>(x, ws8, gamma, b1, b2, gmlp, out);
}

// Round 14
// 89.491 us; speedup vs baseline: 1.0427x; 1.0427x over previous
//
#include <hip/hip_runtime.h>

// B=2,G=1024,S=64,L=16,F=8 -> LF=128, ATT=128, RANK=32, HC=32, NH=4. NWIN=2048.
#define NWIN 2048

// ws layout (BYTE offsets). Total 86528 B (under proven 123392 budget).
#define QKVT8_OFF 0      // uchar [160][128]: rows 0-127 QT_tab^T x256 (fused Wq_u*M, incl 1/sqrt32)
                         //                   rows 128-159 Wkv_u^T x16
#define OT8_OFF  20480   // uchar [128][128]  O^T x128
#define W1T_OFF  36864   // short [128][128]  W1^T bf16 (x1)
#define W2T8_OFF 69632   // uchar [128][128]  W2^T x16
#define CVEC_OFF 86016   // float [128]

typedef __attribute__((ext_vector_type(8))) __bf16 bf16x8;
typedef __attribute__((ext_vector_type(8))) short s16x8;
typedef __attribute__((ext_vector_type(4))) short s16x4;
typedef __attribute__((ext_vector_type(4))) float f32x4;

static __device__ inline short f2bf(float f) {
    __bf16 b = (__bf16)f;
    return __builtin_bit_cast(short, b);
}
static __device__ inline float bf2f(short h) {
    unsigned u = ((unsigned)(unsigned short)h) << 16;
    return __builtin_bit_cast(float, u);
}
static __device__ inline bf16x8 ldbf8(const short* p) {
    return __builtin_bit_cast(bf16x8, *(const s16x8*)p);
}
static __device__ inline unsigned char f2fp8(float v) {
    return (unsigned char)__builtin_amdgcn_cvt_pk_fp8_f32(v, v, 0u, false);
}
static __device__ inline long ld8(const void* p) {
    return *(const long*)p;
}

// ---------------- precompute: fp8 tables (scales exact powers of 2) ----------------
__global__ __launch_bounds__(256) void fam_pre(
    const float* __restrict__ Wq_u, const float* __restrict__ Wq_v,
    const float* __restrict__ Wkv_u, const float* __restrict__ Wkv_v,
    const float* __restrict__ kv_b, const float* __restrict__ Wo_u,
    const float* __restrict__ Wo_v, const float* __restrict__ W1,
    const float* __restrict__ W2, unsigned char* __restrict__ ws8)
{
    const int b = blockIdx.x, tid = threadIdx.x;
    float* cvec = (float*)(ws8 + CVEC_OFF);
    if (b < 16) {
        __shared__ float Wv[4096];   // Wkv_v v-part [r][c]
        __shared__ float Wu[4096];   // Wo_u [att][u]
        __shared__ float N[4096];    // N[h][u][r]
        for (int i = tid; i < 4096; i += 256) {
            int r = i >> 7, c = i & 127;
            Wv[i] = Wkv_v[r*256 + 128 + c];
            Wu[i] = Wo_u[i];
        }
        __syncthreads();
        for (int i = tid; i < 4096; i += 256) {
            int h = i >> 10, u = (i >> 5) & 31, r = i & 31;
            float acc = 0.f;
            for (int c = 0; c < 32; ++c) acc += Wv[r*128 + h*32 + c] * Wu[(h*32 + c)*32 + u];
            N[i] = acc;
        }
        __syncthreads();
        for (int i = tid; i < 1024; i += 256) {
            int jj = i >> 7, hr = i & 127;
            int j = b*8 + jj, h = hr >> 5, r = hr & 31;
            float acc = 0.f;
            for (int u = 0; u < 32; ++u) acc += N[h*1024 + u*32 + r] * Wo_v[u*128 + j];
            ws8[OT8_OFF + j*128 + hr] = f2fp8(acc * 128.f);
        }
    } else if (b < 32) {
        short* w1t = (short*)(ws8 + W1T_OFF);
        int i0 = (b - 16) * 8;
        for (int t = tid; t < 1024; t += 256) {
            int ii = t >> 7, k = t & 127, i = i0 + ii;
            w1t[i*128 + k] = f2bf(W1[k*128 + i]);
        }
    } else if (b < 48) {
        int j0 = (b - 32) * 8;
        for (int t = tid; t < 1024; t += 256) {
            int jj = t >> 7, k = t & 127, j = j0 + jj;
            ws8[W2T8_OFF + j*128 + k] = f2fp8(W2[k*128 + j] * 16.f);
        }
    } else {
        // QKVT slices: sl = 0..7; each builds M redundantly, writes 16 QT rows + 4 KV rows
        const int sl = b - 48;
        __shared__ float Msh[4096];   // M[h][u][r] (incl 1/sqrt32)
        __shared__ float ov[32];
        const float sc = 0.17677669529663687f;  // 1/sqrt(32)
        for (int i = tid; i < 4096; i += 256) {
            int h = i >> 10, u = (i >> 5) & 31, r = i & 31;
            float acc = 0.f;
            for (int c = 0; c < 32; ++c)
                acc += Wq_v[u*128 + h*32 + c] * Wkv_v[r*256 + h*32 + c];
            Msh[i] = acc * sc;
        }
        __syncthreads();
        // QT_tab rows c (= output col): tab[c][k] = sum_u Wq_u[k][u]*M[h(c)][u][r(c)], x256
        for (int i = tid; i < 2048; i += 256) {
            int c = sl*16 + (i >> 7), k = i & 127;
            int h = c >> 5, r = c & 31;
            float acc = 0.f;
            for (int u = 0; u < 32; ++u) acc += Wq_u[k*32 + u] * Msh[h*1024 + u*32 + r];
            ws8[QKVT8_OFF + c*128 + k] = f2fp8(acc * 256.f);
        }
        // KV rows (x16)
        for (int i = tid; i < 512; i += 256) {
            int u = sl*4 + (i >> 7), k = i & 127;
            ws8[QKVT8_OFF + (128 + u)*128 + k] = f2fp8(Wkv_u[k*32 + u] * 16.f);
        }
        if (sl == 0) {
            if (tid < 32) {
                float a = 0.f;
                for (int att = 0; att < 128; ++att) a += kv_b[128 + att] * Wo_u[att*32 + tid];
                ov[tid] = a;
            }
            __syncthreads();
            if (tid < 128) {
                float a = 0.f;
                for (int u = 0; u < 32; ++u) a += ov[u] * Wo_v[u*128 + tid];
                cvec[tid] = a;
            }
        }
    }
}

// ---------------- main fused kernel: 1 block = 1 window, 4 waves ----------------
// R13 kernel with __launch_bounds__(256,4): R13's (256,5) forced x1v spills
// (WRITE_SIZE 65.5->102.7 MB). VGPR cap 128 restores the spill-free budget.
#define SRA 136   // RA8/XB byte/short stride
#define SHQ 40    // KV8 byte stride
#define SHB 72    // HB8/KVT8 byte stride

#define SM_RA8   0        //  8704  h -> pu -> t1 (fp8 [64][SRA])
#define SM_KV8   8704     //  2560  hu_kv x4 fp8 [64][SHQ] (A of scores)
#define SM_KVT8  11264    //  2304  hu_kv^T x4 fp8 [32][SHB] (B of PV)
#define SM_HB8   13568    // 18432  per head [64][SHB]: qt8 then P8; later XB bf16 [64][136]
#define SM_TOTAL 32000

__global__ __launch_bounds__(256, 4) void fam_main(
    const float* __restrict__ x, const unsigned char* __restrict__ ws8,
    const float* __restrict__ gamma, const float* __restrict__ b1,
    const float* __restrict__ b2, const float* __restrict__ gmlp_p,
    float* __restrict__ out)
{
    __shared__ __align__(16) unsigned char SM[SM_TOTAL];
    unsigned char* RA8  = SM + SM_RA8;
    unsigned char* KV8  = SM + SM_KV8;
    unsigned char* KVT8 = SM + SM_KVT8;

    const float* cvec = (const float*)(ws8 + CVEC_OFF);
    const int tid = threadIdx.x;
    const int l   = tid & 63;
    const int wv  = tid >> 6;
    const int l15 = l & 15;
    const int lg  = l >> 4;
    const size_t base = (size_t)blockIdx.x * 8192;
    const float* __restrict__ xw   = x + base;
    float* __restrict__       outw = out + base;
    const int n0 = wv * 32;

    // ---- P1: LN1 -> h (fp8 x1) in RA8 ----
    {
        int s = tid >> 2, c = tid & 3;
        float4 xr1[8];
        float sum = 0.f, sq = 0.f;
        #pragma unroll
        for (int j = 0; j < 8; ++j) {
            xr1[j] = *(const float4*)&xw[s*128 + c*32 + j*4];
            sum += xr1[j].x + xr1[j].y + xr1[j].z + xr1[j].w;
            sq  += xr1[j].x*xr1[j].x + xr1[j].y*xr1[j].y + xr1[j].z*xr1[j].z + xr1[j].w*xr1[j].w;
        }
        sum += __shfl_xor(sum, 1); sq += __shfl_xor(sq, 1);
        sum += __shfl_xor(sum, 2); sq += __shfl_xor(sq, 2);
        float mean = sum * (1.f/128.f);
        float var  = sq * (1.f/128.f) - mean*mean;
        float rinv = rsqrtf(var + 1e-5f);
        #pragma unroll
        for (int j = 0; j < 8; ++j) {
            unsigned w = 0;
            w = __builtin_amdgcn_cvt_pk_fp8_f32((xr1[j].x - mean)*rinv, (xr1[j].y - mean)*rinv, w, false);
            w = __builtin_amdgcn_cvt_pk_fp8_f32((xr1[j].z - mean)*rinv, (xr1[j].w - mean)*rinv, w, true);
            *(unsigned*)&RA8[s*SRA + c*32 + j*4] = w;
        }
    }
    __syncthreads();   // B1

    // ---- P2 (fused): [QT(128) | KV(32)] = h @ QKVT8 ----
    // wave wv: strips wv (qt head wv>>1), wv+4 (qt head 2+(wv>>1)), and 6+wv (kv, wv>=2)
    {
        long bA[4], bB[4], bC[4];
        #pragma unroll
        for (int kb = 0; kb < 4; ++kb) {
            bA[kb] = ld8(ws8 + QKVT8_OFF + (wv*16 + l15)*128 + kb*32 + lg*8);
            bB[kb] = ld8(ws8 + QKVT8_OFF + ((wv + 4)*16 + l15)*128 + kb*32 + lg*8);
        }
        if (wv >= 2) {
            #pragma unroll
            for (int kb = 0; kb < 4; ++kb)
                bC[kb] = ld8(ws8 + QKVT8_OFF + ((6 + wv)*16 + l15)*128 + kb*32 + lg*8);
        }
        unsigned char* HBA = SM + SM_HB8 + (wv >> 1)*4608;        // head wv>>1
        unsigned char* HBB = SM + SM_HB8 + (2 + (wv >> 1))*4608;  // head 2+(wv>>1)
        const int rr = (wv & 1)*16 + l15;                          // col within head
        #pragma unroll
        for (int m = 0; m < 4; ++m) {
            long a[4];
            #pragma unroll
            for (int kb = 0; kb < 4; ++kb)
                a[kb] = ld8(RA8 + (m*16 + l15)*SRA + kb*32 + lg*8);
            f32x4 accA = {0.f,0.f,0.f,0.f}, accB = {0.f,0.f,0.f,0.f};
            #pragma unroll
            for (int kb = 0; kb < 4; ++kb) {
                accA = __builtin_amdgcn_mfma_f32_16x16x32_fp8_fp8(a[kb], bA[kb], accA, 0, 0, 0);
                accB = __builtin_amdgcn_mfma_f32_16x16x32_fp8_fp8(a[kb], bB[kb], accB, 0, 0, 0);
            }
            #pragma unroll
            for (int j = 0; j < 4; ++j) {
                int row = (m*16 + lg*4 + j)*SHB;
                HBA[row + rr] = f2fp8(accA[j] * 0.25f);   // qt8 = qt x64
                HBB[row + rr] = f2fp8(accB[j] * 0.25f);
            }
            if (wv >= 2) {
                f32x4 accC = {0.f,0.f,0.f,0.f};
                #pragma unroll
                for (int kb = 0; kb < 4; ++kb)
                    accC = __builtin_amdgcn_mfma_f32_16x16x32_fp8_fp8(a[kb], bC[kb], accC, 0, 0, 0);
                int u = (wv - 2)*16 + l15;
                #pragma unroll
                for (int j = 0; j < 4; ++j)
                    KV8[(m*16 + lg*4 + j)*SHQ + u] = f2fp8(accC[j] * 0.25f);   // kv x4
                unsigned w = 0;
                w = __builtin_amdgcn_cvt_pk_fp8_f32(accC[0]*0.25f, accC[1]*0.25f, w, false);
                w = __builtin_amdgcn_cvt_pk_fp8_f32(accC[2]*0.25f, accC[3]*0.25f, w, true);
                *(unsigned*)&KVT8[u*SHB + m*16 + lg*4] = w;                    // v x4
            }
        }
    }
    __syncthreads();   // B2: qt8 (all heads), kv, v complete

    // ---- P4/P5: per-head attention (h = wv); qt8 already in HB8h ----
    {
        const int h = wv;
        unsigned char* HB8h = SM + SM_HB8 + h*4608;
        // scores: S^T[t][s] (swapped operands), acc = score x256
        long av[4], bq[4];
        #pragma unroll
        for (int m = 0; m < 4; ++m) av[m] = ld8(KV8 + (m*16 + l15)*SHQ + lg*8);
        #pragma unroll
        for (int n = 0; n < 4; ++n) bq[n] = ld8(HB8h + (n*16 + l15)*SHB + lg*8);
        f32x4 cc[4][4];
        #pragma unroll
        for (int m = 0; m < 4; ++m)
            #pragma unroll
            for (int n = 0; n < 4; ++n) {
                f32x4 z = {0.f, 0.f, 0.f, 0.f};
                cc[m][n] = __builtin_amdgcn_mfma_f32_16x16x32_fp8_fp8(av[m], bq[n], z, 0, 0, 0);
            }
        // softmax over t (no max-reduce; scores tiny), P8 = P x64 (overwrites qt8 after reads)
        #pragma unroll
        for (int n = 0; n < 4; ++n) {
            float e[4][4];
            float sm = 0.f;
            #pragma unroll
            for (int m = 0; m < 4; ++m)
                #pragma unroll
                for (int j = 0; j < 4; ++j) {
                    e[m][j] = __expf(fminf(cc[m][n][j] * 0.00390625f, 30.f));
                    sm += e[m][j];
                }
            sm += __shfl_xor(sm, 16);
            sm += __shfl_xor(sm, 32);
            float rs64 = __builtin_amdgcn_rcpf(sm) * 64.f;
            int srow = (n*16 + l15) * SHB;
            #pragma unroll
            for (int m = 0; m < 4; ++m) {
                unsigned w = 0;
                w = __builtin_amdgcn_cvt_pk_fp8_f32(e[m][0]*rs64, e[m][1]*rs64, w, false);
                w = __builtin_amdgcn_cvt_pk_fp8_f32(e[m][2]*rs64, e[m][3]*rs64, w, true);
                *(unsigned*)&HB8h[srow + m*16 + lg*4] = w;
            }
        }
        // PV: pu = P @ V, acc = pu x256 -> pu8 = pu x8 into RA8
        long a8[4][2], b8[2][2];
        #pragma unroll
        for (int m = 0; m < 4; ++m)
            #pragma unroll
            for (int kb = 0; kb < 2; ++kb)
                a8[m][kb] = ld8(HB8h + (m*16 + l15)*SHB + kb*32 + lg*8);
        #pragma unroll
        for (int nn = 0; nn < 2; ++nn)
            #pragma unroll
            for (int kb = 0; kb < 2; ++kb)
                b8[nn][kb] = ld8(KVT8 + (nn*16 + l15)*SHB + kb*32 + lg*8);
        #pragma unroll
        for (int m = 0; m < 4; ++m)
            #pragma unroll
            for (int nn = 0; nn < 2; ++nn) {
                f32x4 acc = {0.f,0.f,0.f,0.f};
                acc = __builtin_amdgcn_mfma_f32_16x16x32_fp8_fp8(a8[m][0], b8[nn][0], acc, 0, 0, 0);
                acc = __builtin_amdgcn_mfma_f32_16x16x32_fp8_fp8(a8[m][1], b8[nn][1], acc, 0, 0, 0);
                #pragma unroll
                for (int j = 0; j < 4; ++j)
                    RA8[(m*16 + lg*4 + j)*SRA + h*32 + nn*16 + l15] = f2fp8(acc[j] * 0.03125f);
            }
    }
    __syncthreads();   // B3: pu8 in RA8 complete; HB8 dead -> XB

    float x1v[4][2][4];
    short* XB = (short*)(SM + SM_HB8);   // x1/h2 bf16 [64][136]

    // ---- P6: upd = pu8 @ O8 (acc = upd x1024); x1 = x + gm*(acc/1024 + cv) ----
    {
        float xr[4][2][4];
        #pragma unroll
        for (int m = 0; m < 4; ++m)
            #pragma unroll
            for (int nn = 0; nn < 2; ++nn)
                #pragma unroll
                for (int j = 0; j < 4; ++j)
                    xr[m][nn][j] = xw[(m*16 + lg*4 + j)*128 + n0 + nn*16 + l15];
        long bo[2][4];
        float cv[2], gm[2];
        #pragma unroll
        for (int nn = 0; nn < 2; ++nn) {
            int col = n0 + nn*16 + l15;
            #pragma unroll
            for (int kb = 0; kb < 4; ++kb)
                bo[nn][kb] = ld8(ws8 + OT8_OFF + col*128 + kb*32 + lg*8);
            cv[nn] = cvec[col];
            gm[nn] = gamma[col];
        }
        f32x4 acc[4][2];
        #pragma unroll
        for (int m = 0; m < 4; ++m)
            #pragma unroll
            for (int nn = 0; nn < 2; ++nn) acc[m][nn] = (f32x4){0.f,0.f,0.f,0.f};
        #pragma unroll
        for (int m = 0; m < 4; ++m) {
            long a[4];
            #pragma unroll
            for (int kb = 0; kb < 4; ++kb)
                a[kb] = ld8(RA8 + (m*16 + l15)*SRA + kb*32 + lg*8);
            #pragma unroll
            for (int kb = 0; kb < 4; ++kb)
                #pragma unroll
                for (int nn = 0; nn < 2; ++nn)
                    acc[m][nn] = __builtin_amdgcn_mfma_f32_16x16x32_fp8_fp8(a[kb], bo[nn][kb], acc[m][nn], 0, 0, 0);
        }
        // XB does not alias RA8: no interior barrier needed
        #pragma unroll
        for (int m = 0; m < 4; ++m)
            #pragma unroll
            for (int nn = 0; nn < 2; ++nn)
                #pragma unroll
                for (int j = 0; j < 4; ++j) {
                    int row = m*16 + lg*4 + j;
                    float v = xr[m][nn][j] + gm[nn] * (acc[m][nn][j] * 9.765625e-4f + cv[nn]);
                    x1v[m][nn][j] = v;
                    XB[row*SRA + n0 + nn*16 + l15] = f2bf(v);
                }
    }
    __syncthreads();   // B4: x1 bf16 in XB complete

    // ---- P7: LN2 on XB in place (bf16, proven) ----
    {
        int s = tid >> 2, c = tid & 3;
        float sum = 0.f, sq = 0.f;
        #pragma unroll
        for (int jj = 0; jj < 8; ++jj) {
            s16x4 hv = *(const s16x4*)&XB[s*SRA + c*32 + jj*4];
            #pragma unroll
            for (int e = 0; e < 4; ++e) {
                float f = bf2f(hv[e]);
                sum += f; sq += f*f;
            }
        }
        sum += __shfl_xor(sum, 1); sq += __shfl_xor(sq, 1);
        sum += __shfl_xor(sum, 2); sq += __shfl_xor(sq, 2);
        float mean = sum * (1.f/128.f);
        float var  = sq * (1.f/128.f) - mean*mean;
        float rinv = rsqrtf(var + 1e-5f);
        #pragma unroll
        for (int jj = 0; jj < 8; ++jj) {
            s16x4 hv = *(const s16x4*)&XB[s*SRA + c*32 + jj*4];
            s16x4 ov;
            #pragma unroll
            for (int e = 0; e < 4; ++e) ov[e] = f2bf((bf2f(hv[e]) - mean) * rinv);
            *(s16x4*)&XB[s*SRA + c*32 + jj*4] = ov;
        }
    }
    __syncthreads();   // B5: h2 in XB

    // ---- P8: t1 = gelu(h2 @ W1 + b1) (bf16 MFMA) -> t1 x8 fp8 into RA8 ----
    {
        const short* W1t = (const short*)(ws8 + W1T_OFF);
        bf16x8 bw1[2][4];
        float bb1[2];
        #pragma unroll
        for (int nn = 0; nn < 2; ++nn) {
            #pragma unroll
            for (int k = 0; k < 4; ++k)
                bw1[nn][k] = ldbf8(&W1t[(n0 + nn*16 + l15)*128 + k*32 + lg*8]);
            bb1[nn] = b1[n0 + nn*16 + l15];
        }
        #pragma unroll
        for (int m = 0; m < 4; ++m) {
            bf16x8 a[4];
            #pragma unroll
            for (int k = 0; k < 4; ++k)
                a[k] = ldbf8(&XB[(m*16 + l15)*SRA + k*32 + lg*8]);
            #pragma unroll
            for (int nn = 0; nn < 2; ++nn) {
                f32x4 acc = {0.f,0.f,0.f,0.f};
                #pragma unroll
                for (int k = 0; k < 4; ++k)
                    acc = __builtin_amdgcn_mfma_f32_16x16x32_bf16(a[k], bw1[nn][k], acc, 0, 0, 0);
                #pragma unroll
                for (int j = 0; j < 4; ++j) {
                    float t = acc[j] + bb1[nn];
                    float w = -1.5957691216057308f * (t + 0.044715f*t*t*t);
                    float g = t * __builtin_amdgcn_rcpf(1.f + __expf(w));
                    RA8[(m*16 + lg*4 + j)*SRA + n0 + nn*16 + l15] = f2fp8(g * 8.f);
                }
            }
        }
    }
    __syncthreads();   // B6: t1 x8 in RA8

    // ---- P9: m = t1 @ W2 (acc = m x128); out = x1(reg) + gmlp*(acc/128 + b2) ----
    {
        const float gmv = gmlp_p[0];
        long bw[2][4];
        float bb[2];
        #pragma unroll
        for (int nn = 0; nn < 2; ++nn) {
            int col = n0 + nn*16 + l15;
            #pragma unroll
            for (int kb = 0; kb < 4; ++kb)
                bw[nn][kb] = ld8(ws8 + W2T8_OFF + col*128 + kb*32 + lg*8);
            bb[nn] = b2[col];
        }
        #pragma unroll
        for (int m = 0; m < 4; ++m) {
            long a[4];
            #pragma unroll
            for (int kb = 0; kb < 4; ++kb)
                a[kb] = ld8(RA8 + (m*16 + l15)*SRA + kb*32 + lg*8);
            #pragma unroll
            for (int nn = 0; nn < 2; ++nn) {
                f32x4 acc = {0.f,0.f,0.f,0.f};
                #pragma unroll
                for (int kb = 0; kb < 4; ++kb)
                    acc = __builtin_amdgcn_mfma_f32_16x16x32_fp8_fp8(a[kb], bw[nn][kb], acc, 0, 0, 0);
                #pragma unroll
                for (int j = 0; j < 4; ++j)
                    outw[(m*16 + lg*4 + j)*128 + n0 + nn*16 + l15] =
                        x1v[m][nn][j] + gmv * (acc[j] * 0.0078125f + bb[nn]);
            }
        }
    }
}

extern "C" void kernel_launch(void* const* d_in, const int* in_sizes, int n_in,
                              void* d_out, int out_size, void* d_ws, size_t ws_size,
                              hipStream_t stream) {
    const float* x     = (const float*)d_in[0];
    const float* Wq_u  = (const float*)d_in[1];
    const float* Wq_v  = (const float*)d_in[2];
    const float* Wkv_u = (const float*)d_in[3];
    const float* Wkv_v = (const float*)d_in[4];
    const float* kv_b  = (const float*)d_in[5];
    const float* Wo_u  = (const float*)d_in[6];
    const float* Wo_v  = (const float*)d_in[7];
    const float* gamma = (const float*)d_in[8];
    const float* W1    = (const float*)d_in[9];
    const float* b1    = (const float*)d_in[10];
    const float* W2    = (const float*)d_in[11];
    const float* b2    = (const float*)d_in[12];
    const float* gmlp  = (const float*)d_in[13];
    unsigned char* ws8 = (unsigned char*)d_ws;
    float* out = (float*)d_out;

    fam_pre<<<56, 256, 0, stream>>>(Wq_u, Wq_v, Wkv_u, Wkv_v, kv_b, Wo_u, Wo_v, W1, W2, ws8);
    fam_main<<<NWIN, 256, 0, stream>>>(x, ws8, gamma, b1, b2, gmlp, out);
}